// Round 1
// baseline (1001.295 us; speedup 1.0000x reference)
//
#include <hip/hip_runtime.h>
#include <math.h>

#define EPSV 1e-5f

// ---------------------------------------------------------------------------
// Kernel 1: per-feature partial sums over a chunk of B.
// Each thread owns one feature f, loops over b in [b0, b0+chunk).
// Accumulates sum_i (4) and sum_{i>=j} x_i x_j (10) in registers.
// Partials written SoA: part[stat * (NB*F) + nb * F + f]  (coalesced).
// ---------------------------------------------------------------------------
__global__ __launch_bounds__(256) void qbn_stats(
    const float* __restrict__ x, float* __restrict__ part,
    int Fn, int Bn, int chunk, int NB) {
  int f = blockIdx.x * blockDim.x + threadIdx.x;
  if (f >= Fn) return;
  int b0 = blockIdx.y * chunk;
  int b1 = b0 + chunk; if (b1 > Bn) b1 = Bn;

  float s0=0.f,s1=0.f,s2=0.f,s3=0.f;
  float c00=0.f,c10=0.f,c11=0.f,c20=0.f,c21=0.f,c22=0.f;
  float c30=0.f,c31=0.f,c32=0.f,c33=0.f;

  const float4* xp = (const float4*)x;
  #pragma unroll 4
  for (int b = b0; b < b1; ++b) {
    float4 v = xp[(size_t)b * Fn + f];
    s0 += v.x; s1 += v.y; s2 += v.z; s3 += v.w;
    c00 = fmaf(v.x, v.x, c00);
    c10 = fmaf(v.y, v.x, c10);
    c11 = fmaf(v.y, v.y, c11);
    c20 = fmaf(v.z, v.x, c20);
    c21 = fmaf(v.z, v.y, c21);
    c22 = fmaf(v.z, v.z, c22);
    c30 = fmaf(v.w, v.x, c30);
    c31 = fmaf(v.w, v.y, c31);
    c32 = fmaf(v.w, v.z, c32);
    c33 = fmaf(v.w, v.w, c33);
  }

  float vals[14] = {s0,s1,s2,s3,c00,c10,c11,c20,c21,c22,c30,c31,c32,c33};
  size_t stride = (size_t)NB * Fn;
  size_t base = (size_t)blockIdx.y * Fn + f;
  #pragma unroll
  for (int i = 0; i < 14; ++i) part[(size_t)i * stride + base] = vals[i];
}

// ---------------------------------------------------------------------------
// Kernel 2: one thread per feature. Reduce NB partials, form covariance,
// Cholesky, invert L, fold gamma/beta/mean into M (4x4) and bias (4).
// stats layout SoA: stats[k*F + f], k=0..15 = M row-major, 16..19 = bias.
// ---------------------------------------------------------------------------
__global__ __launch_bounds__(256) void qbn_finalize(
    const float* __restrict__ part,
    const float* __restrict__ gamma,
    const float* __restrict__ beta,
    float* __restrict__ stats,
    int Fn, int NB, float invB) {
  int f = blockIdx.x * blockDim.x + threadIdx.x;
  if (f >= Fn) return;

  float acc[14];
  #pragma unroll
  for (int i = 0; i < 14; ++i) acc[i] = 0.f;
  size_t stride = (size_t)NB * Fn;
  for (int nb = 0; nb < NB; ++nb) {
    size_t base = (size_t)nb * Fn + f;
    #pragma unroll
    for (int i = 0; i < 14; ++i) acc[i] += part[(size_t)i * stride + base];
  }

  float m0 = acc[0]*invB, m1 = acc[1]*invB, m2 = acc[2]*invB, m3 = acc[3]*invB;
  // covariance + eps*I   (cov = E[xx^T] - mu mu^T)
  float C00 = acc[4]*invB  - m0*m0 + EPSV;
  float C10 = acc[5]*invB  - m1*m0;
  float C11 = acc[6]*invB  - m1*m1 + EPSV;
  float C20 = acc[7]*invB  - m2*m0;
  float C21 = acc[8]*invB  - m2*m1;
  float C22 = acc[9]*invB  - m2*m2 + EPSV;
  float C30 = acc[10]*invB - m3*m0;
  float C31 = acc[11]*invB - m3*m1;
  float C32 = acc[12]*invB - m3*m2;
  float C33 = acc[13]*invB - m3*m3 + EPSV;

  // Cholesky (lower)
  float L00 = sqrtf(C00);
  float L10 = C10 / L00, L20 = C20 / L00, L30 = C30 / L00;
  float L11 = sqrtf(C11 - L10*L10);
  float L21 = (C21 - L20*L10) / L11;
  float L31 = (C31 - L30*L10) / L11;
  float L22 = sqrtf(C22 - L20*L20 - L21*L21);
  float L32 = (C32 - L30*L20 - L31*L21) / L22;
  float L33 = sqrtf(C33 - L30*L30 - L31*L31 - L32*L32);

  // inverse of lower-triangular L
  float i00 = 1.f/L00, i11 = 1.f/L11, i22 = 1.f/L22, i33 = 1.f/L33;
  float I10 = -i11 * (L10*i00);
  float I20 = -i22 * (L20*i00 + L21*I10);
  float I21 = -i22 * (L21*i11);
  float I30 = -i33 * (L30*i00 + L31*I10 + L32*I20);
  float I31 = -i33 * (L31*i11 + L32*I21);
  float I32 = -i33 * (L32*i22);
  // Linv rows: [i00 0 0 0; I10 i11 0 0; I20 I21 i22 0; I30 I31 I32 i33]
  float Li[4][4] = {{i00, 0.f, 0.f, 0.f},
                    {I10, i11, 0.f, 0.f},
                    {I20, I21, i22, 0.f},
                    {I30, I31, I32, i33}};

  // symmetric gamma from tril order (0,0)(1,0)(1,1)(2,0)(2,1)(2,2)(3,0)(3,1)(3,2)(3,3)
  const float* g = gamma + (size_t)f * 10;
  float G[4][4];
  G[0][0]=g[0];
  G[1][0]=G[0][1]=g[1]; G[1][1]=g[2];
  G[2][0]=G[0][2]=g[3]; G[2][1]=G[1][2]=g[4]; G[2][2]=g[5];
  G[3][0]=G[0][3]=g[6]; G[3][1]=G[1][3]=g[7]; G[3][2]=G[2][3]=g[8]; G[3][3]=g[9];

  // M = G * Linv
  float M[4][4];
  #pragma unroll
  for (int i = 0; i < 4; ++i)
    #pragma unroll
    for (int j = 0; j < 4; ++j) {
      float s = 0.f;
      #pragma unroll
      for (int k = 0; k < 4; ++k) s += G[i][k] * Li[k][j];
      M[i][j] = s;
    }

  // bias = beta - M * mean
  const float* bt = beta + (size_t)f * 4;
  float mu[4] = {m0, m1, m2, m3};
  float bias[4];
  #pragma unroll
  for (int i = 0; i < 4; ++i) {
    float s = bt[i];
    #pragma unroll
    for (int j = 0; j < 4; ++j) s -= M[i][j] * mu[j];
    bias[i] = s;
  }

  #pragma unroll
  for (int i = 0; i < 4; ++i)
    #pragma unroll
    for (int j = 0; j < 4; ++j)
      stats[(size_t)(i*4+j) * Fn + f] = M[i][j];
  #pragma unroll
  for (int i = 0; i < 4; ++i)
    stats[(size_t)(16+i) * Fn + f] = bias[i];
}

// ---------------------------------------------------------------------------
// Kernel 3: out[b,f,:] = M_f * x[b,f,:] + bias_f
// Each thread owns one feature, loads M/bias once into registers, loops over
// a B-chunk. float4 in / float4 out, lane-contiguous.
// ---------------------------------------------------------------------------
__global__ __launch_bounds__(256) void qbn_apply(
    const float* __restrict__ x,
    const float* __restrict__ stats,
    float* __restrict__ out,
    int Fn, int Bn, int chunk) {
  int f = blockIdx.x * blockDim.x + threadIdx.x;
  if (f >= Fn) return;
  int b0 = blockIdx.y * chunk;
  int b1 = b0 + chunk; if (b1 > Bn) b1 = Bn;

  float M[16], bias[4];
  #pragma unroll
  for (int k = 0; k < 16; ++k) M[k] = stats[(size_t)k * Fn + f];
  #pragma unroll
  for (int k = 0; k < 4; ++k) bias[k] = stats[(size_t)(16+k) * Fn + f];

  const float4* xp = (const float4*)x;
  float4* op = (float4*)out;
  #pragma unroll 2
  for (int b = b0; b < b1; ++b) {
    size_t idx = (size_t)b * Fn + f;
    float4 v = xp[idx];
    float4 r;
    r.x = fmaf(M[0],  v.x, fmaf(M[1],  v.y, fmaf(M[2],  v.z, fmaf(M[3],  v.w, bias[0]))));
    r.y = fmaf(M[4],  v.x, fmaf(M[5],  v.y, fmaf(M[6],  v.z, fmaf(M[7],  v.w, bias[1]))));
    r.z = fmaf(M[8],  v.x, fmaf(M[9],  v.y, fmaf(M[10], v.z, fmaf(M[11], v.w, bias[2]))));
    r.w = fmaf(M[12], v.x, fmaf(M[13], v.y, fmaf(M[14], v.z, fmaf(M[15], v.w, bias[3]))));
    op[idx] = r;
  }
}

extern "C" void kernel_launch(void* const* d_in, const int* in_sizes, int n_in,
                              void* d_out, int out_size, void* d_ws, size_t ws_size,
                              hipStream_t stream) {
  const float* x     = (const float*)d_in[0];
  const float* gamma = (const float*)d_in[1];
  const float* beta  = (const float*)d_in[2];
  float* out = (float*)d_out;

  const int Fn = in_sizes[1] / 10;           // 2048
  const int Bn = in_sizes[0] / (Fn * 4);     // 16384

  // workspace layout: stats [20*F floats] | partials [NB * F * 14 floats]
  float* stats = (float*)d_ws;
  float* part  = stats + (size_t)20 * Fn;
  size_t avail_floats = ws_size / 4;
  size_t part_avail = avail_floats > (size_t)20 * Fn ? avail_floats - (size_t)20 * Fn : 0;

  int NB = 128;                               // B-chunks for stats pass
  while (NB > 1 && (size_t)NB * 14 * Fn > part_avail) NB >>= 1;
  int chunk = (Bn + NB - 1) / NB;

  dim3 blk(256);
  dim3 gF((Fn + 255) / 256);

  qbn_stats<<<dim3(gF.x, NB), blk, 0, stream>>>(x, part, Fn, Bn, chunk, NB);
  qbn_finalize<<<gF, blk, 0, stream>>>(part, gamma, beta, stats, Fn, NB, 1.0f / (float)Bn);

  const int NB2 = 128;
  int chunk2 = (Bn + NB2 - 1) / NB2;
  qbn_apply<<<dim3(gF.x, NB2), blk, 0, stream>>>(x, stats, out, Fn, Bn, chunk2);
}